// Round 12
// baseline (290.404 us; speedup 1.0000x reference)
//
#include <hip/hip_runtime.h>
#include <math.h>

#define DIMC 256
#define HW   16384
#define NB   8
#define HID  512
#define NE   4
#define RNK  128

typedef __bf16 bf16x8 __attribute__((ext_vector_type(8)));
typedef float  f32x4  __attribute__((ext_vector_type(4)));
typedef float  f32x16 __attribute__((ext_vector_type(16)));

__device__ __forceinline__ unsigned short f2bf(float f) {
  unsigned u = __builtin_bit_cast(unsigned, f);
  u += 0x7FFFu + ((u >> 16) & 1u);          // round-to-nearest-even
  return (unsigned short)(u >> 16);
}
__device__ __forceinline__ unsigned pack2(float a, float b) {
  return (unsigned)f2bf(a) | ((unsigned)f2bf(b) << 16);
}
__device__ __forceinline__ float bf2f(unsigned short u) {
  unsigned v = ((unsigned)u) << 16;
  return __builtin_bit_cast(float, v);
}

// ---------------------------------------------------------------------------
// Kernel 1: per-(b,c) plane: xsum = sum(x), hsum = sum(gelu(highpass3x3(x)))
// ---------------------------------------------------------------------------
#define CPAD 136
__global__ __launch_bounds__(256) void k_conv_reduce(const float* __restrict__ x,
                                                     float* __restrict__ xsum,
                                                     float* __restrict__ hsum) {
  __shared__ unsigned short sp[128 * CPAD];  // 34816 B
  __shared__ float red[8];
  const int p = blockIdx.x;
  const int tid = threadIdx.x;
  const float4* img4 = (const float4*)(x + (size_t)p * HW);
#pragma unroll
  for (int u = 0; u < 16; ++u) {
    const int unit = tid + 256 * u;
    const float4 v = img4[unit];
    const int row = unit >> 5, xq = unit & 31;
    uint2 w;
    w.x = pack2(v.x, v.y);
    w.y = pack2(v.z, v.w);
    *(uint2*)&sp[row * CPAD + xq * 4] = w;
  }
  __syncthreads();

  float xacc = 0.f, hacc = 0.f;
#pragma unroll
  for (int u = 0; u < 4; ++u) {
    const int seg = tid + 256 * u;
    const int row = seg >> 3, x0 = (seg & 7) * 16;
    float S[16], c[16];
#pragma unroll
    for (int j = 0; j < 16; ++j) S[j] = 0.f;
#pragma unroll
    for (int dr = -1; dr <= 1; ++dr) {
      const int r2 = row + dr;
      float v[18];
      if ((unsigned)r2 <= 127u) {
        const unsigned short* rp = sp + r2 * CPAD + x0;
        const uint4 q0 = *(const uint4*)(rp);
        const uint4 q1 = *(const uint4*)(rp + 8);
        v[0]  = (x0 > 0)        ? bf2f(rp[-1]) : 0.f;
        v[17] = (x0 + 16 < 128) ? bf2f(rp[16]) : 0.f;
        v[1] = bf2f((unsigned short)(q0.x & 0xffff)); v[2] = bf2f((unsigned short)(q0.x >> 16));
        v[3] = bf2f((unsigned short)(q0.y & 0xffff)); v[4] = bf2f((unsigned short)(q0.y >> 16));
        v[5] = bf2f((unsigned short)(q0.z & 0xffff)); v[6] = bf2f((unsigned short)(q0.z >> 16));
        v[7] = bf2f((unsigned short)(q0.w & 0xffff)); v[8] = bf2f((unsigned short)(q0.w >> 16));
        v[9]  = bf2f((unsigned short)(q1.x & 0xffff)); v[10] = bf2f((unsigned short)(q1.x >> 16));
        v[11] = bf2f((unsigned short)(q1.y & 0xffff)); v[12] = bf2f((unsigned short)(q1.y >> 16));
        v[13] = bf2f((unsigned short)(q1.z & 0xffff)); v[14] = bf2f((unsigned short)(q1.z >> 16));
        v[15] = bf2f((unsigned short)(q1.w & 0xffff)); v[16] = bf2f((unsigned short)(q1.w >> 16));
      } else {
#pragma unroll
        for (int j = 0; j < 18; ++j) v[j] = 0.f;
      }
      if (dr == 0) {
#pragma unroll
        for (int j = 0; j < 16; ++j) c[j] = v[j + 1];
      }
#pragma unroll
      for (int j = 0; j < 16; ++j) S[j] += v[j] + v[j + 1] + v[j + 2];
    }
#pragma unroll
    for (int j = 0; j < 16; ++j) {
      const float h = 9.f * c[j] - S[j];
      hacc += 0.5f * h * (1.f + erff(h * 0.70710678118654752f));
      xacc += c[j];
    }
  }
#pragma unroll
  for (int off = 32; off > 0; off >>= 1) {
    xacc += __shfl_down(xacc, off);
    hacc += __shfl_down(hacc, off);
  }
  const int wid = tid >> 6, lane = tid & 63;
  if (lane == 0) { red[wid] = xacc; red[4 + wid] = hacc; }
  __syncthreads();
  if (tid == 0) {
    xsum[p] = red[0] + red[1] + red[2] + red[3];
    hsum[p] = red[4] + red[5] + red[6] + red[7];
  }
}

// ---------------------------------------------------------------------------
// Gating stages (r7 wide versions, proven)
// ---------------------------------------------------------------------------
__global__ __launch_bounds__(256) void k_gate_t1(
    const float* __restrict__ hsum, const float* __restrict__ w1,
    const float* __restrict__ b1, float* __restrict__ t1) {
  const int blk = blockIdx.x;
  const int b = blk >> 7;
  const int o = (blk & 127) * 4 + (threadIdx.x >> 6);
  const int lane = threadIdx.x & 63;
  const float4 h = *(const float4*)(hsum + b * DIMC + lane * 4);
  const float4 w = *(const float4*)(w1 + (size_t)o * DIMC + lane * 4);
  float acc = h.x * w.x + h.y * w.y + h.z * w.z + h.w * w.w;
#pragma unroll
  for (int off = 32; off > 0; off >>= 1) acc += __shfl_down(acc, off);
  if (lane == 0) {
    acc = acc * (1.f / 16384.f) + b1[o];
    t1[b * HID + o] = 0.5f * acc * (1.f + erff(acc * 0.70710678118654752f));
  }
}

__global__ __launch_bounds__(256) void k_gate_fe(
    const float* __restrict__ t1, const float* __restrict__ w2,
    const float* __restrict__ b2, float* __restrict__ fe) {
  const int blk = blockIdx.x;
  const int b = blk >> 6;
  const int o = (blk & 63) * 4 + (threadIdx.x >> 6);
  const int lane = threadIdx.x & 63;
  const float* tr = t1 + b * HID + lane * 8;
  const float* wr = w2 + (size_t)o * HID + lane * 8;
  const float4 ta = *(const float4*)tr,  tb = *(const float4*)(tr + 4);
  const float4 wa = *(const float4*)wr,  wb = *(const float4*)(wr + 4);
  float acc = ta.x * wa.x + ta.y * wa.y + ta.z * wa.z + ta.w * wa.w
            + tb.x * wb.x + tb.y * wb.y + tb.z * wb.z + tb.w * wb.w;
#pragma unroll
  for (int off = 32; off > 0; off >>= 1) acc += __shfl_down(acc, off);
  if (lane == 0) fe[b * DIMC + o] = acc + b2[o];
}

__global__ __launch_bounds__(256) void k_gate_fin(
    const float* __restrict__ xsum, const float* __restrict__ fe,
    const float* __restrict__ gw, const float* __restrict__ fgw,
    float* __restrict__ gates, float* __restrict__ gsumv, int* __restrict__ sel) {
  __shared__ float slog[NB][NE];
  const int wave = threadIdx.x >> 6, lane = threadIdx.x & 63;
  const int e = wave;
  const float4 g1 = *(const float4*)(gw + e * DIMC + lane * 4);
  const float4 g2 = *(const float4*)(fgw + e * DIMC + lane * 4);
  for (int b = 0; b < NB; ++b) {
    const float4 p = *(const float4*)(xsum + b * DIMC + lane * 4);
    const float4 f = *(const float4*)(fe + b * DIMC + lane * 4);
    float acc = (p.x * g1.x + p.y * g1.y + p.z * g1.z + p.w * g1.w) * (1.f / 16384.f)
              + f.x * g2.x + f.y * g2.y + f.z * g2.z + f.w * g2.w;
#pragma unroll
    for (int off = 32; off > 0; off >>= 1) acc += __shfl_down(acc, off);
    if (lane == 0) slog[b][e] = acc;
  }
  __syncthreads();
  if (threadIdx.x < NB) {
    const int b = threadIdx.x;
    float l[4] = {slog[b][0], slog[b][1], slog[b][2], slog[b][3]};
    const float m = fmaxf(fmaxf(l[0], l[1]), fmaxf(l[2], l[3]));
    float g[4];
    float ssum = 0.f;
    for (int e2 = 0; e2 < 4; ++e2) { g[e2] = expf(l[e2] - m); ssum += g[e2]; }
    for (int e2 = 0; e2 < 4; ++e2) g[e2] /= ssum;
    int i1 = 0;
    for (int e2 = 1; e2 < 4; ++e2) if (g[e2] > g[i1]) i1 = e2;
    int i2 = -1;
    for (int e2 = 0; e2 < 4; ++e2) {
      if (e2 == i1) continue;
      if (i2 < 0 || g[e2] > g[i2]) i2 = e2;
    }
    for (int e2 = 0; e2 < 4; ++e2)
      gates[b * 4 + e2] = (e2 == i1) ? g[i1] : ((e2 == i2) ? g[i2] : 0.f);
    gsumv[b] = g[i1] + g[i2];
    sel[b * 2 + 0] = i1;
    sel[b * 2 + 1] = i2;
  }
}

// ---------------------------------------------------------------------------
// Kernel 3: Q2[e,o,r] = sum_d Wp[o,d] * p2[e,d,r]  (1024-block, proven)
// ---------------------------------------------------------------------------
__global__ __launch_bounds__(128) void k_q2(const float* __restrict__ wp,
                                            const float* __restrict__ p2,
                                            float* __restrict__ q2) {
  const int eo = blockIdx.x;
  const int e = eo >> 8, o = eo & 255;
  const int r = threadIdx.x;
  const float* p2e = p2 + (size_t)e * DIMC * RNK;
  const float* wrow = wp + (size_t)o * DIMC;
  float acc = 0.f;
  for (int d = 0; d < DIMC; ++d) acc += wrow[d] * p2e[d * RNK + r];
  q2[(size_t)eo * RNK + r] = acc;
}

// ---------------------------------------------------------------------------
// Kernel 4: assemble bf16 weights in MFMA-FRAGMENT-MAJOR layout (proven).
// Granule (8 bf16) rows of: [b][rowblk][ks][h][r][8]
//   A1/A2: 8 rowblk x 16 ks (K=256);  A3: 8 rowblk x 32 ks (K=512:
//   ks 0..15 = gate-scaled Q2 over rank, ks 16..31 = gsum*Wp over d).
// ---------------------------------------------------------------------------
__global__ __launch_bounds__(256) void k_build(
    const float* __restrict__ p0, const float* __restrict__ p1,
    const float* __restrict__ wp, const float* __restrict__ q2,
    const float* __restrict__ gates, const float* __restrict__ gsumv,
    const int* __restrict__ sel,
    unsigned* __restrict__ A1u, unsigned* __restrict__ A2u,
    unsigned* __restrict__ A3u) {
  const int total = NB * 32768;              // granules
  for (int id = blockIdx.x * 256 + threadIdx.x; id < total;
       id += gridDim.x * 256) {
    const int b = id >> 15;
    const int gi = id & 32767;
    uint4 wv;
    unsigned* dst;
    if (gi < 16384) {
      const int t = gi >> 13;                // 0: A1(p0), 1: A2(p1)
      const int gj = gi & 8191;
      const int rowblk = gj >> 10, ks = (gj >> 6) & 15;
      const int h = (gj >> 5) & 1, r = gj & 31;
      const int row = rowblk * 32 + r;
      const int e = sel[b * 2 + (row >> 7)];
      const float* src = (t ? p1 : p0) + ((size_t)e * 128 + (row & 127)) * 256
                       + ks * 16 + h * 8;
      const float4 v0 = *(const float4*)src;
      const float4 v1 = *(const float4*)(src + 4);
      wv.x = pack2(v0.x, v0.y); wv.y = pack2(v0.z, v0.w);
      wv.z = pack2(v1.x, v1.y); wv.w = pack2(v1.z, v1.w);
      dst = (t ? A2u : A1u) + (size_t)b * 32768 + gj * 4;
    } else {
      const int gj = gi - 16384;             // 0..16383
      const int rowblk = gj >> 11, ks = (gj >> 6) & 31;
      const int h = (gj >> 5) & 1, r = gj & 31;
      const int o = rowblk * 32 + r;
      const int k = ks * 16 + h * 8;
      float v[8];
      if (k < 256) {                         // y-half: gate-scaled Q2
        const int e = sel[b * 2 + (k >> 7)];
        const float gsc = gates[b * 4 + e];
        const float* qq = q2 + ((size_t)e * 256 + o) * RNK + (k & 127);
#pragma unroll
        for (int j = 0; j < 8; ++j) v[j] = gsc * qq[j];
      } else {                               // x-half: gsum * Wp
        const float gs = gsumv[b];
        const float* wr = wp + (size_t)o * DIMC + (k - 256);
#pragma unroll
        for (int j = 0; j < 8; ++j) v[j] = gs * wr[j];
      }
      wv.x = pack2(v[0], v[1]); wv.y = pack2(v[2], v[3]);
      wv.z = pack2(v[4], v[5]); wv.w = pack2(v[6], v[7]);
      dst = A3u + (size_t)b * 65536 + gj * 4;
    }
    *(uint4*)dst = wv;
  }
}

// ---------------------------------------------------------------------------
// Kernel 5: MFMA main, 32x32x16, 32-PX TILES for 3 blocks/CU.
// 4096 blocks (batch = bid&7 -> XCD-affine weights), 512 thr / 8 waves,
// wave = 32 rows x 32 px.  LDS 2 x 16 KB.  One f32x16 acc per GEMM phase
// (peak AGPR 32) + no A-prefetch => unified VGPR <= ~85 so launch_bounds
// (512,6) = 24 waves/CU = 3 resident blocks; cross-block phase overlap
// raises HBM duty (r11's 2-block config idled HBM during GEMM phases).
// LDS per tensor: [dblk=d/8][px ^ (dblk&7)][8 bf16] = 16 KB.
// ---------------------------------------------------------------------------
__global__ __launch_bounds__(512, 6) void k_main_mfma(
    const float* __restrict__ x, const float* __restrict__ shr,
    const unsigned short* __restrict__ A1b, const unsigned short* __restrict__ A2b,
    const unsigned short* __restrict__ A3b, float* __restrict__ out) {
  __shared__ unsigned short XF[8192];        // 16 KB
  __shared__ unsigned short SF[8192];        // 16 KB
  const int tid = threadIdx.x;
  const int b = blockIdx.x & 7;              // batch -> XCD affinity
  const int tile = blockIdx.x >> 3;          // 0..511
  const int nb0 = tile * 32;
  const int wave = tid >> 6;                 // 0..7
  const int lane = tid & 63;
  const int r32 = lane & 31;
  const int h = lane >> 5;
  const int wrow = wave * 32;
  const size_t pbase = (size_t)b * DIMC * HW + nb0;

  // ---- stage x, shr (transpose-on-load, conflict-free b128 writes) ----
#pragma unroll
  for (int pass = 0; pass < 2; ++pass) {
    const int unit = pass * 512 + tid;       // 1024 units = 32 dblk x 32 px
    const int px = unit & 31;
    const int dblk = unit >> 5;              // 0..31
    const float* xc = x   + pbase + (size_t)(dblk * 8) * HW + px;
    const float* sc = shr + pbase + (size_t)(dblk * 8) * HW + px;
    float vx[8], vs[8];
#pragma unroll
    for (int jj = 0; jj < 8; ++jj) {
      vx[jj] = xc[(size_t)jj * HW];
      vs[jj] = sc[(size_t)jj * HW];
    }
    const int o = dblk * 256 + ((px ^ (dblk & 7)) << 3);
    uint4 wv;
    wv.x = pack2(vx[0], vx[1]); wv.y = pack2(vx[2], vx[3]);
    wv.z = pack2(vx[4], vx[5]); wv.w = pack2(vx[6], vx[7]);
    *(uint4*)&XF[o] = wv;
    uint4 sv;
    sv.x = pack2(vs[0], vs[1]); sv.y = pack2(vs[2], vs[3]);
    sv.z = pack2(vs[4], vs[5]); sv.w = pack2(vs[6], vs[7]);
    *(uint4*)&SF[o] = sv;
  }
  __syncthreads();

  const unsigned short* A1w = A1b + (size_t)(b * 8 + wave) * 8192;
  const unsigned short* A2w = A2b + (size_t)(b * 8 + wave) * 8192;
  const unsigned short* A3w = A3b + (size_t)(b * 8 + wave) * 16384;

  // ---- GEMM2: bb = A2 @ shared ----
  f32x16 accB = (f32x16)0.f;
#pragma unroll
  for (int ks = 0; ks < 16; ++ks) {
    const bf16x8 a = *(const bf16x8*)(A2w + ks * 512 + lane * 8);
    const int dblkB = ks * 2 + h;
    const int eb = dblkB * 256 + ((r32 ^ (dblkB & 7)) << 3);
    const bf16x8 b0 = *(const bf16x8*)&SF[eb];
    accB = __builtin_amdgcn_mfma_f32_32x32x16_bf16(a, b0, accB, 0, 0, 0);
  }

  // ---- GEMM1: a = A1 @ x ----
  f32x16 accA = (f32x16)0.f;
#pragma unroll
  for (int ks = 0; ks < 16; ++ks) {
    const bf16x8 a = *(const bf16x8*)(A1w + ks * 512 + lane * 8);
    const int dblkB = ks * 2 + h;
    const int eb = dblkB * 256 + ((r32 ^ (dblkB & 7)) << 3);
    const bf16x8 b0 = *(const bf16x8*)&XF[eb];
    accA = __builtin_amdgcn_mfma_f32_32x32x16_bf16(a, b0, accA, 0, 0, 0);
  }
  __syncthreads();                           // all SF reads done (y overwrites)

  // ---- y = a * silu(bb) -> SF (accA/accB die here) ----
#pragma unroll
  for (int q = 0; q < 4; ++q) {
    const int dblk = wave * 4 + q;
    const int sw = dblk & 7;
    float y0[4];
#pragma unroll
    for (int i = 0; i < 4; ++i) {
      const float bA = accB[q * 4 + i];
      y0[i] = accA[q * 4 + i] * (bA / (1.f + __expf(-bA)));
    }
    uint2 w0; w0.x = pack2(y0[0], y0[1]); w0.y = pack2(y0[2], y0[3]);
    *(uint2*)&SF[dblk * 256 + ((r32 ^ sw) << 3) + h * 4] = w0;
  }

  // ---- GEMM3 x-half (reads only XF — overlaps other waves' y-writes) ----
  f32x16 accO = (f32x16)0.f;
  {
    const unsigned short* A3x = A3w + 16 * 512;
#pragma unroll
    for (int ks = 0; ks < 16; ++ks) {
      const bf16x8 a = *(const bf16x8*)(A3x + ks * 512 + lane * 8);
      const int dblkB = ks * 2 + h;
      const int eb = dblkB * 256 + ((r32 ^ (dblkB & 7)) << 3);
      const bf16x8 b0 = *(const bf16x8*)&XF[eb];
      accO = __builtin_amdgcn_mfma_f32_32x32x16_bf16(a, b0, accO, 0, 0, 0);
    }
  }
  __syncthreads();                           // Y ready

  // ---- GEMM3 y-half: accO += A3[:, 0:256] @ y ----
#pragma unroll
  for (int ks = 0; ks < 16; ++ks) {
    const bf16x8 a = *(const bf16x8*)(A3w + ks * 512 + lane * 8);
    const int dblkB = ks * 2 + h;
    const int eb = dblkB * 256 + ((r32 ^ (dblkB & 7)) << 3);
    const bf16x8 b0 = *(const bf16x8*)&SF[eb];
    accO = __builtin_amdgcn_mfma_f32_32x32x16_bf16(a, b0, accO, 0, 0, 0);
  }

  // ---- store out (fp32): row = wrow + (r&3) + 8*(r>>2) + 4h, col = px ----
  {
    float* ob = out + pbase;
#pragma unroll
    for (int r = 0; r < 16; ++r) {
      const int row = wrow + (r & 3) + 8 * (r >> 2) + 4 * h;
      ob[(size_t)row * HW + r32] = accO[r];
    }
  }
}

// ---------------------------------------------------------------------------
extern "C" void kernel_launch(void* const* d_in, const int* in_sizes, int n_in,
                              void* d_out, int out_size, void* d_ws, size_t ws_size,
                              hipStream_t stream) {
  (void)in_sizes; (void)n_in; (void)out_size; (void)ws_size;
  const float* x   = (const float*)d_in[0];
  const float* shr = (const float*)d_in[1];
  const float* w1  = (const float*)d_in[2];
  const float* b1  = (const float*)d_in[3];
  const float* w2  = (const float*)d_in[4];
  const float* b2  = (const float*)d_in[5];
  const float* gw  = (const float*)d_in[6];
  const float* fgw = (const float*)d_in[7];
  const float* p0  = (const float*)d_in[8];
  const float* p1  = (const float*)d_in[9];
  const float* p2  = (const float*)d_in[10];
  const float* wp  = (const float*)d_in[11];
  float* out = (float*)d_out;

  float* ws    = (float*)d_ws;
  float* xsum  = ws;                         // 2048 f32
  float* hsum  = ws + 2048;                  // 2048 f32
  float* gates = ws + 4096;                  // 32 f32
  float* gsumv = ws + 4128;                  // 8 f32
  int*   sel   = (int*)(ws + 4136);          // 16 ints
  float* q2    = ws + 4152;                  // 131072 f32
  unsigned* A1u = (unsigned*)(ws + 135224);  // 262144 u32 (bf16 pairs)
  unsigned* A2u = A1u + NB * 256 * 128;      // 262144 u32
  unsigned* A3u = A2u + NB * 256 * 128;      // 524288 u32
  float* t1g   = (float*)(A3u + NB * 256 * 256);  // 4096 f32
  float* feg   = t1g + NB * HID;                  // 2048 f32

  k_conv_reduce<<<NB * DIMC, 256, 0, stream>>>(x, xsum, hsum);
  k_gate_t1<<<1024, 256, 0, stream>>>(hsum, w1, b1, t1g);
  k_gate_fe<<<512, 256, 0, stream>>>(t1g, w2, b2, feg);
  k_gate_fin<<<1, 256, 0, stream>>>(xsum, feg, gw, fgw, gates, gsumv, sel);
  k_q2<<<NE * DIMC, 128, 0, stream>>>(wp, p2, q2);
  k_build<<<512, 256, 0, stream>>>(p0, p1, wp, q2, gates, gsumv, sel, A1u, A2u, A3u);
  k_main_mfma<<<4096, 512, 0, stream>>>(x, shr,
      (const unsigned short*)A1u, (const unsigned short*)A2u,
      (const unsigned short*)A3u, out);
}

// Round 13
// 289.855 us; speedup vs baseline: 1.0019x; 1.0019x over previous
//
#include <hip/hip_runtime.h>
#include <math.h>

#define DIMC 256
#define HW   16384
#define NB   8
#define HID  512
#define NE   4
#define RNK  128

typedef __bf16 bf16x8 __attribute__((ext_vector_type(8)));
typedef float  f32x4  __attribute__((ext_vector_type(4)));
typedef float  f32x16 __attribute__((ext_vector_type(16)));

// one-instruction RTNE pack of 2 floats -> 2 bf16 (low=a, high=b).
// Same rounding as the compiler's (__bf16) cast (verified r8: identical absmax),
// but kept in the scalar consume-immediately form that doesn't spill.
__device__ __forceinline__ unsigned pack2(float a, float b) {
  unsigned r;
  asm("v_cvt_pk_bf16_f32 %0, %1, %2" : "=v"(r) : "v"(a), "v"(b));
  return r;
}
__device__ __forceinline__ float bf2f(unsigned short u) {
  unsigned v = ((unsigned)u) << 16;
  return __builtin_bit_cast(float, v);
}

// ---------------------------------------------------------------------------
// Kernel 1: per-(b,c) plane: xsum = sum(x), hsum = sum(gelu(highpass3x3(x)))
// ---------------------------------------------------------------------------
#define CPAD 136
__global__ __launch_bounds__(256) void k_conv_reduce(const float* __restrict__ x,
                                                     float* __restrict__ xsum,
                                                     float* __restrict__ hsum) {
  __shared__ unsigned short sp[128 * CPAD];  // 34816 B
  __shared__ float red[8];
  const int p = blockIdx.x;
  const int tid = threadIdx.x;
  const float4* img4 = (const float4*)(x + (size_t)p * HW);
#pragma unroll
  for (int u = 0; u < 16; ++u) {
    const int unit = tid + 256 * u;
    const float4 v = img4[unit];
    const int row = unit >> 5, xq = unit & 31;
    uint2 w;
    w.x = pack2(v.x, v.y);
    w.y = pack2(v.z, v.w);
    *(uint2*)&sp[row * CPAD + xq * 4] = w;
  }
  __syncthreads();

  float xacc = 0.f, hacc = 0.f;
#pragma unroll
  for (int u = 0; u < 4; ++u) {
    const int seg = tid + 256 * u;
    const int row = seg >> 3, x0 = (seg & 7) * 16;
    float S[16], c[16];
#pragma unroll
    for (int j = 0; j < 16; ++j) S[j] = 0.f;
#pragma unroll
    for (int dr = -1; dr <= 1; ++dr) {
      const int r2 = row + dr;
      float v[18];
      if ((unsigned)r2 <= 127u) {
        const unsigned short* rp = sp + r2 * CPAD + x0;
        const uint4 q0 = *(const uint4*)(rp);
        const uint4 q1 = *(const uint4*)(rp + 8);
        v[0]  = (x0 > 0)        ? bf2f(rp[-1]) : 0.f;
        v[17] = (x0 + 16 < 128) ? bf2f(rp[16]) : 0.f;
        v[1] = bf2f((unsigned short)(q0.x & 0xffff)); v[2] = bf2f((unsigned short)(q0.x >> 16));
        v[3] = bf2f((unsigned short)(q0.y & 0xffff)); v[4] = bf2f((unsigned short)(q0.y >> 16));
        v[5] = bf2f((unsigned short)(q0.z & 0xffff)); v[6] = bf2f((unsigned short)(q0.z >> 16));
        v[7] = bf2f((unsigned short)(q0.w & 0xffff)); v[8] = bf2f((unsigned short)(q0.w >> 16));
        v[9]  = bf2f((unsigned short)(q1.x & 0xffff)); v[10] = bf2f((unsigned short)(q1.x >> 16));
        v[11] = bf2f((unsigned short)(q1.y & 0xffff)); v[12] = bf2f((unsigned short)(q1.y >> 16));
        v[13] = bf2f((unsigned short)(q1.z & 0xffff)); v[14] = bf2f((unsigned short)(q1.z >> 16));
        v[15] = bf2f((unsigned short)(q1.w & 0xffff)); v[16] = bf2f((unsigned short)(q1.w >> 16));
      } else {
#pragma unroll
        for (int j = 0; j < 18; ++j) v[j] = 0.f;
      }
      if (dr == 0) {
#pragma unroll
        for (int j = 0; j < 16; ++j) c[j] = v[j + 1];
      }
#pragma unroll
      for (int j = 0; j < 16; ++j) S[j] += v[j] + v[j + 1] + v[j + 2];
    }
#pragma unroll
    for (int j = 0; j < 16; ++j) {
      const float h = 9.f * c[j] - S[j];
      hacc += 0.5f * h * (1.f + erff(h * 0.70710678118654752f));
      xacc += c[j];
    }
  }
#pragma unroll
  for (int off = 32; off > 0; off >>= 1) {
    xacc += __shfl_down(xacc, off);
    hacc += __shfl_down(hacc, off);
  }
  const int wid = tid >> 6, lane = tid & 63;
  if (lane == 0) { red[wid] = xacc; red[4 + wid] = hacc; }
  __syncthreads();
  if (tid == 0) {
    xsum[p] = red[0] + red[1] + red[2] + red[3];
    hsum[p] = red[4] + red[5] + red[6] + red[7];
  }
}

// ---------------------------------------------------------------------------
// Gating stages (r7 wide versions, proven)
// ---------------------------------------------------------------------------
__global__ __launch_bounds__(256) void k_gate_t1(
    const float* __restrict__ hsum, const float* __restrict__ w1,
    const float* __restrict__ b1, float* __restrict__ t1) {
  const int blk = blockIdx.x;
  const int b = blk >> 7;
  const int o = (blk & 127) * 4 + (threadIdx.x >> 6);
  const int lane = threadIdx.x & 63;
  const float4 h = *(const float4*)(hsum + b * DIMC + lane * 4);
  const float4 w = *(const float4*)(w1 + (size_t)o * DIMC + lane * 4);
  float acc = h.x * w.x + h.y * w.y + h.z * w.z + h.w * w.w;
#pragma unroll
  for (int off = 32; off > 0; off >>= 1) acc += __shfl_down(acc, off);
  if (lane == 0) {
    acc = acc * (1.f / 16384.f) + b1[o];
    t1[b * HID + o] = 0.5f * acc * (1.f + erff(acc * 0.70710678118654752f));
  }
}

__global__ __launch_bounds__(256) void k_gate_fe(
    const float* __restrict__ t1, const float* __restrict__ w2,
    const float* __restrict__ b2, float* __restrict__ fe) {
  const int blk = blockIdx.x;
  const int b = blk >> 6;
  const int o = (blk & 63) * 4 + (threadIdx.x >> 6);
  const int lane = threadIdx.x & 63;
  const float* tr = t1 + b * HID + lane * 8;
  const float* wr = w2 + (size_t)o * HID + lane * 8;
  const float4 ta = *(const float4*)tr,  tb = *(const float4*)(tr + 4);
  const float4 wa = *(const float4*)wr,  wb = *(const float4*)(wr + 4);
  float acc = ta.x * wa.x + ta.y * wa.y + ta.z * wa.z + ta.w * wa.w
            + tb.x * wb.x + tb.y * wb.y + tb.z * wb.z + tb.w * wb.w;
#pragma unroll
  for (int off = 32; off > 0; off >>= 1) acc += __shfl_down(acc, off);
  if (lane == 0) fe[b * DIMC + o] = acc + b2[o];
}

__global__ __launch_bounds__(256) void k_gate_fin(
    const float* __restrict__ xsum, const float* __restrict__ fe,
    const float* __restrict__ gw, const float* __restrict__ fgw,
    float* __restrict__ gates, float* __restrict__ gsumv, int* __restrict__ sel) {
  __shared__ float slog[NB][NE];
  const int wave = threadIdx.x >> 6, lane = threadIdx.x & 63;
  const int e = wave;
  const float4 g1 = *(const float4*)(gw + e * DIMC + lane * 4);
  const float4 g2 = *(const float4*)(fgw + e * DIMC + lane * 4);
  for (int b = 0; b < NB; ++b) {
    const float4 p = *(const float4*)(xsum + b * DIMC + lane * 4);
    const float4 f = *(const float4*)(fe + b * DIMC + lane * 4);
    float acc = (p.x * g1.x + p.y * g1.y + p.z * g1.z + p.w * g1.w) * (1.f / 16384.f)
              + f.x * g2.x + f.y * g2.y + f.z * g2.z + f.w * g2.w;
#pragma unroll
    for (int off = 32; off > 0; off >>= 1) acc += __shfl_down(acc, off);
    if (lane == 0) slog[b][e] = acc;
  }
  __syncthreads();
  if (threadIdx.x < NB) {
    const int b = threadIdx.x;
    float l[4] = {slog[b][0], slog[b][1], slog[b][2], slog[b][3]};
    const float m = fmaxf(fmaxf(l[0], l[1]), fmaxf(l[2], l[3]));
    float g[4];
    float ssum = 0.f;
    for (int e2 = 0; e2 < 4; ++e2) { g[e2] = expf(l[e2] - m); ssum += g[e2]; }
    for (int e2 = 0; e2 < 4; ++e2) g[e2] /= ssum;
    int i1 = 0;
    for (int e2 = 1; e2 < 4; ++e2) if (g[e2] > g[i1]) i1 = e2;
    int i2 = -1;
    for (int e2 = 0; e2 < 4; ++e2) {
      if (e2 == i1) continue;
      if (i2 < 0 || g[e2] > g[i2]) i2 = e2;
    }
    for (int e2 = 0; e2 < 4; ++e2)
      gates[b * 4 + e2] = (e2 == i1) ? g[i1] : ((e2 == i2) ? g[i2] : 0.f);
    gsumv[b] = g[i1] + g[i2];
    sel[b * 2 + 0] = i1;
    sel[b * 2 + 1] = i2;
  }
}

// ---------------------------------------------------------------------------
// Kernel 3: Q2[e,o,r] = sum_d Wp[o,d] * p2[e,d,r]  (1024-block, proven)
// ---------------------------------------------------------------------------
__global__ __launch_bounds__(128) void k_q2(const float* __restrict__ wp,
                                            const float* __restrict__ p2,
                                            float* __restrict__ q2) {
  const int eo = blockIdx.x;
  const int e = eo >> 8, o = eo & 255;
  const int r = threadIdx.x;
  const float* p2e = p2 + (size_t)e * DIMC * RNK;
  const float* wrow = wp + (size_t)o * DIMC;
  float acc = 0.f;
  for (int d = 0; d < DIMC; ++d) acc += wrow[d] * p2e[d * RNK + r];
  q2[(size_t)eo * RNK + r] = acc;
}

// ---------------------------------------------------------------------------
// Kernel 4: assemble bf16 weights in MFMA-FRAGMENT-MAJOR layout (proven).
// Granule (8 bf16) rows of: [b][rowblk][ks][h][r][8]
//   A1/A2: 8 rowblk x 16 ks (K=256);  A3: 8 rowblk x 32 ks (K=512:
//   ks 0..15 = gate-scaled Q2 over rank, ks 16..31 = gsum*Wp over d).
// ---------------------------------------------------------------------------
__global__ __launch_bounds__(256) void k_build(
    const float* __restrict__ p0, const float* __restrict__ p1,
    const float* __restrict__ wp, const float* __restrict__ q2,
    const float* __restrict__ gates, const float* __restrict__ gsumv,
    const int* __restrict__ sel,
    unsigned* __restrict__ A1u, unsigned* __restrict__ A2u,
    unsigned* __restrict__ A3u) {
  const int total = NB * 32768;              // granules
  for (int id = blockIdx.x * 256 + threadIdx.x; id < total;
       id += gridDim.x * 256) {
    const int b = id >> 15;
    const int gi = id & 32767;
    uint4 wv;
    unsigned* dst;
    if (gi < 16384) {
      const int t = gi >> 13;                // 0: A1(p0), 1: A2(p1)
      const int gj = gi & 8191;
      const int rowblk = gj >> 10, ks = (gj >> 6) & 15;
      const int h = (gj >> 5) & 1, r = gj & 31;
      const int row = rowblk * 32 + r;
      const int e = sel[b * 2 + (row >> 7)];
      const float* src = (t ? p1 : p0) + ((size_t)e * 128 + (row & 127)) * 256
                       + ks * 16 + h * 8;
      const float4 v0 = *(const float4*)src;
      const float4 v1 = *(const float4*)(src + 4);
      wv.x = pack2(v0.x, v0.y); wv.y = pack2(v0.z, v0.w);
      wv.z = pack2(v1.x, v1.y); wv.w = pack2(v1.z, v1.w);
      dst = (t ? A2u : A1u) + (size_t)b * 32768 + gj * 4;
    } else {
      const int gj = gi - 16384;             // 0..16383
      const int rowblk = gj >> 11, ks = (gj >> 6) & 31;
      const int h = (gj >> 5) & 1, r = gj & 31;
      const int o = rowblk * 32 + r;
      const int k = ks * 16 + h * 8;
      float v[8];
      if (k < 256) {                         // y-half: gate-scaled Q2
        const int e = sel[b * 2 + (k >> 7)];
        const float gsc = gates[b * 4 + e];
        const float* qq = q2 + ((size_t)e * 256 + o) * RNK + (k & 127);
#pragma unroll
        for (int j = 0; j < 8; ++j) v[j] = gsc * qq[j];
      } else {                               // x-half: gsum * Wp
        const float gs = gsumv[b];
        const float* wr = wp + (size_t)o * DIMC + (k - 256);
#pragma unroll
        for (int j = 0; j < 8; ++j) v[j] = gs * wr[j];
      }
      wv.x = pack2(v[0], v[1]); wv.y = pack2(v[2], v[3]);
      wv.z = pack2(v[4], v[5]); wv.w = pack2(v[6], v[7]);
      dst = A3u + (size_t)b * 65536 + gj * 4;
    }
    *(uint4*)dst = wv;
  }
}

// ---------------------------------------------------------------------------
// Kernel 5: MFMA main, 32x32x16, r11 structure (proven best, no spill):
// 64-px tiles, 2048 blocks (2/CU), 512 thr / 8 waves, wave = 32 rows x 64 px;
// depth-2 A-fragment prefetch; v_cvt_pk_bf16_f32 for all f32->bf16.
// LDS per tensor: [dblk=d/8][px ^ (dblk&7)][8 bf16] = 32 KB.
// ---------------------------------------------------------------------------
__global__ __launch_bounds__(512, 4) void k_main_mfma(
    const float* __restrict__ x, const float* __restrict__ shr,
    const unsigned short* __restrict__ A1b, const unsigned short* __restrict__ A2b,
    const unsigned short* __restrict__ A3b, float* __restrict__ out) {
  __shared__ unsigned short XF[16384];
  __shared__ unsigned short SF[16384];
  const int tid = threadIdx.x;
  const int b = blockIdx.x & 7;              // batch -> XCD affinity
  const int tile = blockIdx.x >> 3;
  const int nb0 = tile * 64;
  const int wave = tid >> 6;                 // 0..7
  const int lane = tid & 63;
  const int r32 = lane & 31;
  const int h = lane >> 5;
  const int wrow = wave * 32;
  const size_t pbase = (size_t)b * DIMC * HW + nb0;

  // ---- stage x, shr (transpose-on-load, conflict-free b128 writes) ----
  {
    const int px = lane;
#pragma unroll
    for (int pass = 0; pass < 4; ++pass) {
      const int dblk = pass * 8 + wave;      // 0..31
      const float* xc = x   + pbase + (size_t)(dblk * 8) * HW + px;
      const float* sc = shr + pbase + (size_t)(dblk * 8) * HW + px;
      float vx[8], vs[8];
#pragma unroll
      for (int jj = 0; jj < 8; ++jj) {
        vx[jj] = xc[(size_t)jj * HW];
        vs[jj] = sc[(size_t)jj * HW];
      }
      const int o = dblk * 512 + ((px ^ (dblk & 7)) << 3);
      uint4 wv;
      wv.x = pack2(vx[0], vx[1]); wv.y = pack2(vx[2], vx[3]);
      wv.z = pack2(vx[4], vx[5]); wv.w = pack2(vx[6], vx[7]);
      *(uint4*)&XF[o] = wv;
      uint4 sv;
      sv.x = pack2(vs[0], vs[1]); sv.y = pack2(vs[2], vs[3]);
      sv.z = pack2(vs[4], vs[5]); sv.w = pack2(vs[6], vs[7]);
      *(uint4*)&SF[o] = sv;
    }
  }
  __syncthreads();

  const unsigned short* A1w = A1b + (size_t)(b * 8 + wave) * 8192;
  const unsigned short* A2w = A2b + (size_t)(b * 8 + wave) * 8192;
  const unsigned short* A3w = A3b + (size_t)(b * 8 + wave) * 16384;

  // ---- GEMM2: bb = A2 @ shared  (depth-2 A prefetch) ----
  f32x16 accB0 = (f32x16)0.f, accB1 = (f32x16)0.f;
  {
    bf16x8 ap0 = *(const bf16x8*)(A2w + lane * 8);
    bf16x8 ap1 = *(const bf16x8*)(A2w + 512 + lane * 8);
#pragma unroll
    for (int ks = 0; ks < 16; ++ks) {
      const bf16x8 a = ap0;
      ap0 = ap1;
      if (ks < 14) ap1 = *(const bf16x8*)(A2w + (ks + 2) * 512 + lane * 8);
      const int dblkB = ks * 2 + h;
      const int eb = dblkB * 512 + ((r32 ^ (dblkB & 7)) << 3);
      const bf16x8 b0 = *(const bf16x8*)&SF[eb];
      const bf16x8 b1 = *(const bf16x8*)&SF[eb + 256];
      accB0 = __builtin_amdgcn_mfma_f32_32x32x16_bf16(a, b0, accB0, 0, 0, 0);
      accB1 = __builtin_amdgcn_mfma_f32_32x32x16_bf16(a, b1, accB1, 0, 0, 0);
    }
  }

  // ---- GEMM1: a = A1 @ x  (depth-2 A prefetch) ----
  f32x16 accA0 = (f32x16)0.f, accA1 = (f32x16)0.f;
  {
    bf16x8 ap0 = *(const bf16x8*)(A1w + lane * 8);
    bf16x8 ap1 = *(const bf16x8*)(A1w + 512 + lane * 8);
#pragma unroll
    for (int ks = 0; ks < 16; ++ks) {
      const bf16x8 a = ap0;
      ap0 = ap1;
      if (ks < 14) ap1 = *(const bf16x8*)(A1w + (ks + 2) * 512 + lane * 8);
      const int dblkB = ks * 2 + h;
      const int eb = dblkB * 512 + ((r32 ^ (dblkB & 7)) << 3);
      const bf16x8 b0 = *(const bf16x8*)&XF[eb];
      const bf16x8 b1 = *(const bf16x8*)&XF[eb + 256];
      accA0 = __builtin_amdgcn_mfma_f32_32x32x16_bf16(a, b0, accA0, 0, 0, 0);
      accA1 = __builtin_amdgcn_mfma_f32_32x32x16_bf16(a, b1, accA1, 0, 0, 0);
    }
  }
  __syncthreads();                           // all SF reads done (y overwrites)

  // ---- y = a * silu(bb) -> SF (accA/accB die here) ----
#pragma unroll
  for (int q = 0; q < 4; ++q) {
    const int dblk = wave * 4 + q;
    const int sw = dblk & 7;
    const int base = dblk * 512 + h * 4;
    float y0[4], y1[4];
#pragma unroll
    for (int i = 0; i < 4; ++i) {
      const float bA = accB0[q * 4 + i];
      const float bBv = accB1[q * 4 + i];
      y0[i] = accA0[q * 4 + i] * (bA / (1.f + __expf(-bA)));
      y1[i] = accA1[q * 4 + i] * (bBv / (1.f + __expf(-bBv)));
    }
    uint2 w0; w0.x = pack2(y0[0], y0[1]); w0.y = pack2(y0[2], y0[3]);
    *(uint2*)&SF[base + ((r32 ^ sw) << 3)] = w0;
    uint2 w1; w1.x = pack2(y1[0], y1[1]); w1.y = pack2(y1[2], y1[3]);
    *(uint2*)&SF[base + (((32 + r32) ^ sw) << 3)] = w1;
  }

  // ---- GEMM3 x-half (reads only XF — overlaps other waves' y-writes) ----
  f32x16 accO0 = (f32x16)0.f, accO1 = (f32x16)0.f;
  {
    const unsigned short* A3x = A3w + 16 * 512;
    bf16x8 ap0 = *(const bf16x8*)(A3x + lane * 8);
    bf16x8 ap1 = *(const bf16x8*)(A3x + 512 + lane * 8);
#pragma unroll
    for (int ks = 0; ks < 16; ++ks) {
      const bf16x8 a = ap0;
      ap0 = ap1;
      if (ks < 14) ap1 = *(const bf16x8*)(A3x + (ks + 2) * 512 + lane * 8);
      const int dblkB = ks * 2 + h;
      const int eb = dblkB * 512 + ((r32 ^ (dblkB & 7)) << 3);
      const bf16x8 b0 = *(const bf16x8*)&XF[eb];
      const bf16x8 b1 = *(const bf16x8*)&XF[eb + 256];
      accO0 = __builtin_amdgcn_mfma_f32_32x32x16_bf16(a, b0, accO0, 0, 0, 0);
      accO1 = __builtin_amdgcn_mfma_f32_32x32x16_bf16(a, b1, accO1, 0, 0, 0);
    }
  }
  __syncthreads();                           // Y ready

  // ---- GEMM3 y-half: accO += A3[:, 0:256] @ y  (depth-2 A prefetch) ----
  {
    bf16x8 ap0 = *(const bf16x8*)(A3w + lane * 8);
    bf16x8 ap1 = *(const bf16x8*)(A3w + 512 + lane * 8);
#pragma unroll
    for (int ks = 0; ks < 16; ++ks) {
      const bf16x8 a = ap0;
      ap0 = ap1;
      if (ks < 14) ap1 = *(const bf16x8*)(A3w + (ks + 2) * 512 + lane * 8);
      const int dblkB = ks * 2 + h;
      const int eb = dblkB * 512 + ((r32 ^ (dblkB & 7)) << 3);
      const bf16x8 b0 = *(const bf16x8*)&SF[eb];
      const bf16x8 b1 = *(const bf16x8*)&SF[eb + 256];
      accO0 = __builtin_amdgcn_mfma_f32_32x32x16_bf16(a, b0, accO0, 0, 0, 0);
      accO1 = __builtin_amdgcn_mfma_f32_32x32x16_bf16(a, b1, accO1, 0, 0, 0);
    }
  }

  // ---- store out (fp32): row = wrow + (r&3) + 8*(r>>2) + 4h, col = px ----
  {
    float* ob = out + pbase;
#pragma unroll
    for (int r = 0; r < 16; ++r) {
      const int row = wrow + (r & 3) + 8 * (r >> 2) + 4 * h;
      ob[(size_t)row * HW + r32] = accO0[r];
      ob[(size_t)row * HW + 32 + r32] = accO1[r];
    }
  }
}

// ---------------------------------------------------------------------------
extern "C" void kernel_launch(void* const* d_in, const int* in_sizes, int n_in,
                              void* d_out, int out_size, void* d_ws, size_t ws_size,
                              hipStream_t stream) {
  (void)in_sizes; (void)n_in; (void)out_size; (void)ws_size;
  const float* x   = (const float*)d_in[0];
  const float* shr = (const float*)d_in[1];
  const float* w1  = (const float*)d_in[2];
  const float* b1  = (const float*)d_in[3];
  const float* w2  = (const float*)d_in[4];
  const float* b2  = (const float*)d_in[5];
  const float* gw  = (const float*)d_in[6];
  const float* fgw = (const float*)d_in[7];
  const float* p0  = (const float*)d_in[8];
  const float* p1  = (const float*)d_in[9];
  const float* p2  = (const float*)d_in[10];
  const float* wp  = (const float*)d_in[11];
  float* out = (float*)d_out;

  float* ws    = (float*)d_ws;
  float* xsum  = ws;                         // 2048 f32
  float* hsum  = ws + 2048;                  // 2048 f32
  float* gates = ws + 4096;                  // 32 f32
  float* gsumv = ws + 4128;                  // 8 f32
  int*   sel   = (int*)(ws + 4136);          // 16 ints
  float* q2    = ws + 4152;                  // 131072 f32
  unsigned* A1u = (unsigned*)(ws + 135224);  // 262144 u32 (bf16 pairs)
  unsigned* A2u = A1u + NB * 256 * 128;      // 262144 u32
  unsigned* A3u = A2u + NB * 256 * 128;      // 524288 u32
  float* t1g   = (float*)(A3u + NB * 256 * 256);  // 4096 f32
  float* feg   = t1g + NB * HID;                  // 2048 f32

  k_conv_reduce<<<NB * DIMC, 256, 0, stream>>>(x, xsum, hsum);
  k_gate_t1<<<1024, 256, 0, stream>>>(hsum, w1, b1, t1g);
  k_gate_fe<<<512, 256, 0, stream>>>(t1g, w2, b2, feg);
  k_gate_fin<<<1, 256, 0, stream>>>(xsum, feg, gw, fgw, gates, gsumv, sel);
  k_q2<<<NE * DIMC, 128, 0, stream>>>(wp, p2, q2);
  k_build<<<512, 256, 0, stream>>>(p0, p1, wp, q2, gates, gsumv, sel, A1u, A2u, A3u);
  k_main_mfma<<<2048, 512, 0, stream>>>(x, shr,
      (const unsigned short*)A1u, (const unsigned short*)A2u,
      (const unsigned short*)A3u, out);
}

// Round 14
// 260.666 us; speedup vs baseline: 1.1141x; 1.1120x over previous
//
#include <hip/hip_runtime.h>
#include <math.h>

#define DIMC 256
#define HW   16384
#define NB   8
#define HID  512
#define NE   4
#define RNK  128

typedef __bf16 bf16x8 __attribute__((ext_vector_type(8)));
typedef float  f32x4  __attribute__((ext_vector_type(4)));
typedef float  f32x16 __attribute__((ext_vector_type(16)));

__device__ __forceinline__ unsigned short f2bf(float f) {
  unsigned u = __builtin_bit_cast(unsigned, f);
  u += 0x7FFFu + ((u >> 16) & 1u);          // round-to-nearest-even
  return (unsigned short)(u >> 16);
}
__device__ __forceinline__ unsigned pack2(float a, float b) {
  return (unsigned)f2bf(a) | ((unsigned)f2bf(b) << 16);
}
__device__ __forceinline__ float bf2f(unsigned short u) {
  unsigned v = ((unsigned)u) << 16;
  return __builtin_bit_cast(float, v);
}

// ---------------------------------------------------------------------------
// Kernel 1: per-(b,c) plane: xsum = sum(x), hsum = sum(gelu(highpass3x3(x)))
// ---------------------------------------------------------------------------
#define CPAD 136
__global__ __launch_bounds__(256) void k_conv_reduce(const float* __restrict__ x,
                                                     float* __restrict__ xsum,
                                                     float* __restrict__ hsum) {
  __shared__ unsigned short sp[128 * CPAD];  // 34816 B
  __shared__ float red[8];
  const int p = blockIdx.x;
  const int tid = threadIdx.x;
  const float4* img4 = (const float4*)(x + (size_t)p * HW);
#pragma unroll
  for (int u = 0; u < 16; ++u) {
    const int unit = tid + 256 * u;
    const float4 v = img4[unit];
    const int row = unit >> 5, xq = unit & 31;
    uint2 w;
    w.x = pack2(v.x, v.y);
    w.y = pack2(v.z, v.w);
    *(uint2*)&sp[row * CPAD + xq * 4] = w;
  }
  __syncthreads();

  float xacc = 0.f, hacc = 0.f;
#pragma unroll
  for (int u = 0; u < 4; ++u) {
    const int seg = tid + 256 * u;
    const int row = seg >> 3, x0 = (seg & 7) * 16;
    float S[16], c[16];
#pragma unroll
    for (int j = 0; j < 16; ++j) S[j] = 0.f;
#pragma unroll
    for (int dr = -1; dr <= 1; ++dr) {
      const int r2 = row + dr;
      float v[18];
      if ((unsigned)r2 <= 127u) {
        const unsigned short* rp = sp + r2 * CPAD + x0;
        const uint4 q0 = *(const uint4*)(rp);
        const uint4 q1 = *(const uint4*)(rp + 8);
        v[0]  = (x0 > 0)        ? bf2f(rp[-1]) : 0.f;
        v[17] = (x0 + 16 < 128) ? bf2f(rp[16]) : 0.f;
        v[1] = bf2f((unsigned short)(q0.x & 0xffff)); v[2] = bf2f((unsigned short)(q0.x >> 16));
        v[3] = bf2f((unsigned short)(q0.y & 0xffff)); v[4] = bf2f((unsigned short)(q0.y >> 16));
        v[5] = bf2f((unsigned short)(q0.z & 0xffff)); v[6] = bf2f((unsigned short)(q0.z >> 16));
        v[7] = bf2f((unsigned short)(q0.w & 0xffff)); v[8] = bf2f((unsigned short)(q0.w >> 16));
        v[9]  = bf2f((unsigned short)(q1.x & 0xffff)); v[10] = bf2f((unsigned short)(q1.x >> 16));
        v[11] = bf2f((unsigned short)(q1.y & 0xffff)); v[12] = bf2f((unsigned short)(q1.y >> 16));
        v[13] = bf2f((unsigned short)(q1.z & 0xffff)); v[14] = bf2f((unsigned short)(q1.z >> 16));
        v[15] = bf2f((unsigned short)(q1.w & 0xffff)); v[16] = bf2f((unsigned short)(q1.w >> 16));
      } else {
#pragma unroll
        for (int j = 0; j < 18; ++j) v[j] = 0.f;
      }
      if (dr == 0) {
#pragma unroll
        for (int j = 0; j < 16; ++j) c[j] = v[j + 1];
      }
#pragma unroll
      for (int j = 0; j < 16; ++j) S[j] += v[j] + v[j + 1] + v[j + 2];
    }
#pragma unroll
    for (int j = 0; j < 16; ++j) {
      const float h = 9.f * c[j] - S[j];
      hacc += 0.5f * h * (1.f + erff(h * 0.70710678118654752f));
      xacc += c[j];
    }
  }
#pragma unroll
  for (int off = 32; off > 0; off >>= 1) {
    xacc += __shfl_down(xacc, off);
    hacc += __shfl_down(hacc, off);
  }
  const int wid = tid >> 6, lane = tid & 63;
  if (lane == 0) { red[wid] = xacc; red[4 + wid] = hacc; }
  __syncthreads();
  if (tid == 0) {
    xsum[p] = red[0] + red[1] + red[2] + red[3];
    hsum[p] = red[4] + red[5] + red[6] + red[7];
  }
}

// ---------------------------------------------------------------------------
// Gating stages (r7 wide versions, proven)
// ---------------------------------------------------------------------------
__global__ __launch_bounds__(256) void k_gate_t1(
    const float* __restrict__ hsum, const float* __restrict__ w1,
    const float* __restrict__ b1, float* __restrict__ t1) {
  const int blk = blockIdx.x;
  const int b = blk >> 7;
  const int o = (blk & 127) * 4 + (threadIdx.x >> 6);
  const int lane = threadIdx.x & 63;
  const float4 h = *(const float4*)(hsum + b * DIMC + lane * 4);
  const float4 w = *(const float4*)(w1 + (size_t)o * DIMC + lane * 4);
  float acc = h.x * w.x + h.y * w.y + h.z * w.z + h.w * w.w;
#pragma unroll
  for (int off = 32; off > 0; off >>= 1) acc += __shfl_down(acc, off);
  if (lane == 0) {
    acc = acc * (1.f / 16384.f) + b1[o];
    t1[b * HID + o] = 0.5f * acc * (1.f + erff(acc * 0.70710678118654752f));
  }
}

__global__ __launch_bounds__(256) void k_gate_fe(
    const float* __restrict__ t1, const float* __restrict__ w2,
    const float* __restrict__ b2, float* __restrict__ fe) {
  const int blk = blockIdx.x;
  const int b = blk >> 6;
  const int o = (blk & 63) * 4 + (threadIdx.x >> 6);
  const int lane = threadIdx.x & 63;
  const float* tr = t1 + b * HID + lane * 8;
  const float* wr = w2 + (size_t)o * HID + lane * 8;
  const float4 ta = *(const float4*)tr,  tb = *(const float4*)(tr + 4);
  const float4 wa = *(const float4*)wr,  wb = *(const float4*)(wr + 4);
  float acc = ta.x * wa.x + ta.y * wa.y + ta.z * wa.z + ta.w * wa.w
            + tb.x * wb.x + tb.y * wb.y + tb.z * wb.z + tb.w * wb.w;
#pragma unroll
  for (int off = 32; off > 0; off >>= 1) acc += __shfl_down(acc, off);
  if (lane == 0) fe[b * DIMC + o] = acc + b2[o];
}

__global__ __launch_bounds__(256) void k_gate_fin(
    const float* __restrict__ xsum, const float* __restrict__ fe,
    const float* __restrict__ gw, const float* __restrict__ fgw,
    float* __restrict__ gates, float* __restrict__ gsumv, int* __restrict__ sel) {
  __shared__ float slog[NB][NE];
  const int wave = threadIdx.x >> 6, lane = threadIdx.x & 63;
  const int e = wave;
  const float4 g1 = *(const float4*)(gw + e * DIMC + lane * 4);
  const float4 g2 = *(const float4*)(fgw + e * DIMC + lane * 4);
  for (int b = 0; b < NB; ++b) {
    const float4 p = *(const float4*)(xsum + b * DIMC + lane * 4);
    const float4 f = *(const float4*)(fe + b * DIMC + lane * 4);
    float acc = (p.x * g1.x + p.y * g1.y + p.z * g1.z + p.w * g1.w) * (1.f / 16384.f)
              + f.x * g2.x + f.y * g2.y + f.z * g2.z + f.w * g2.w;
#pragma unroll
    for (int off = 32; off > 0; off >>= 1) acc += __shfl_down(acc, off);
    if (lane == 0) slog[b][e] = acc;
  }
  __syncthreads();
  if (threadIdx.x < NB) {
    const int b = threadIdx.x;
    float l[4] = {slog[b][0], slog[b][1], slog[b][2], slog[b][3]};
    const float m = fmaxf(fmaxf(l[0], l[1]), fmaxf(l[2], l[3]));
    float g[4];
    float ssum = 0.f;
    for (int e2 = 0; e2 < 4; ++e2) { g[e2] = expf(l[e2] - m); ssum += g[e2]; }
    for (int e2 = 0; e2 < 4; ++e2) g[e2] /= ssum;
    int i1 = 0;
    for (int e2 = 1; e2 < 4; ++e2) if (g[e2] > g[i1]) i1 = e2;
    int i2 = -1;
    for (int e2 = 0; e2 < 4; ++e2) {
      if (e2 == i1) continue;
      if (i2 < 0 || g[e2] > g[i2]) i2 = e2;
    }
    for (int e2 = 0; e2 < 4; ++e2)
      gates[b * 4 + e2] = (e2 == i1) ? g[i1] : ((e2 == i2) ? g[i2] : 0.f);
    gsumv[b] = g[i1] + g[i2];
    sel[b * 2 + 0] = i1;
    sel[b * 2 + 1] = i2;
  }
}

// ---------------------------------------------------------------------------
// Kernel 3: Q2[e,o,r] = sum_d Wp[o,d] * p2[e,d,r]  (1024-block, proven)
// ---------------------------------------------------------------------------
__global__ __launch_bounds__(128) void k_q2(const float* __restrict__ wp,
                                            const float* __restrict__ p2,
                                            float* __restrict__ q2) {
  const int eo = blockIdx.x;
  const int e = eo >> 8, o = eo & 255;
  const int r = threadIdx.x;
  const float* p2e = p2 + (size_t)e * DIMC * RNK;
  const float* wrow = wp + (size_t)o * DIMC;
  float acc = 0.f;
  for (int d = 0; d < DIMC; ++d) acc += wrow[d] * p2e[d * RNK + r];
  q2[(size_t)eo * RNK + r] = acc;
}

// ---------------------------------------------------------------------------
// Kernel 4: assemble bf16 weights in MFMA-FRAGMENT-MAJOR layout (proven).
// Granule (8 bf16) rows of: [b][rowblk][ks][h][r][8]
//   A1/A2: 8 rowblk x 16 ks (K=256);  A3: 8 rowblk x 32 ks (K=512:
//   ks 0..15 = gate-scaled Q2 over rank, ks 16..31 = gsum*Wp over d).
// ---------------------------------------------------------------------------
__global__ __launch_bounds__(256) void k_build(
    const float* __restrict__ p0, const float* __restrict__ p1,
    const float* __restrict__ wp, const float* __restrict__ q2,
    const float* __restrict__ gates, const float* __restrict__ gsumv,
    const int* __restrict__ sel,
    unsigned* __restrict__ A1u, unsigned* __restrict__ A2u,
    unsigned* __restrict__ A3u) {
  const int total = NB * 32768;              // granules
  for (int id = blockIdx.x * 256 + threadIdx.x; id < total;
       id += gridDim.x * 256) {
    const int b = id >> 15;
    const int gi = id & 32767;
    uint4 wv;
    unsigned* dst;
    if (gi < 16384) {
      const int t = gi >> 13;                // 0: A1(p0), 1: A2(p1)
      const int gj = gi & 8191;
      const int rowblk = gj >> 10, ks = (gj >> 6) & 15;
      const int h = (gj >> 5) & 1, r = gj & 31;
      const int row = rowblk * 32 + r;
      const int e = sel[b * 2 + (row >> 7)];
      const float* src = (t ? p1 : p0) + ((size_t)e * 128 + (row & 127)) * 256
                       + ks * 16 + h * 8;
      const float4 v0 = *(const float4*)src;
      const float4 v1 = *(const float4*)(src + 4);
      wv.x = pack2(v0.x, v0.y); wv.y = pack2(v0.z, v0.w);
      wv.z = pack2(v1.x, v1.y); wv.w = pack2(v1.z, v1.w);
      dst = (t ? A2u : A1u) + (size_t)b * 32768 + gj * 4;
    } else {
      const int gj = gi - 16384;             // 0..16383
      const int rowblk = gj >> 11, ks = (gj >> 6) & 31;
      const int h = (gj >> 5) & 1, r = gj & 31;
      const int o = rowblk * 32 + r;
      const int k = ks * 16 + h * 8;
      float v[8];
      if (k < 256) {                         // y-half: gate-scaled Q2
        const int e = sel[b * 2 + (k >> 7)];
        const float gsc = gates[b * 4 + e];
        const float* qq = q2 + ((size_t)e * 256 + o) * RNK + (k & 127);
#pragma unroll
        for (int j = 0; j < 8; ++j) v[j] = gsc * qq[j];
      } else {                               // x-half: gsum * Wp
        const float gs = gsumv[b];
        const float* wr = wp + (size_t)o * DIMC + (k - 256);
#pragma unroll
        for (int j = 0; j < 8; ++j) v[j] = gs * wr[j];
      }
      wv.x = pack2(v[0], v[1]); wv.y = pack2(v[2], v[3]);
      wv.z = pack2(v[4], v[5]); wv.w = pack2(v[6], v[7]);
      dst = A3u + (size_t)b * 65536 + gj * 4;
    }
    *(uint4*)dst = wv;
  }
}

// ---------------------------------------------------------------------------
// Kernel 5: MFMA main, 32x32x16, r11 structure (measured best, no spill):
// 64-px tiles, 2048 blocks (2/CU), 512 thr / 8 waves, wave = 32 rows x 64 px;
// depth-2 A-fragment prefetch; hand-rolled f2bf pack2 (schedulable AND
// pressure-safe — native casts spilled [r8], asm cvt_pk fenced the
// scheduler [r13]).  LDS per tensor: [dblk=d/8][px ^ (dblk&7)][8 bf16].
// ---------------------------------------------------------------------------
__global__ __launch_bounds__(512, 4) void k_main_mfma(
    const float* __restrict__ x, const float* __restrict__ shr,
    const unsigned short* __restrict__ A1b, const unsigned short* __restrict__ A2b,
    const unsigned short* __restrict__ A3b, float* __restrict__ out) {
  __shared__ unsigned short XF[16384];
  __shared__ unsigned short SF[16384];
  const int tid = threadIdx.x;
  const int b = blockIdx.x & 7;              // batch -> XCD affinity
  const int tile = blockIdx.x >> 3;
  const int nb0 = tile * 64;
  const int wave = tid >> 6;                 // 0..7
  const int lane = tid & 63;
  const int r32 = lane & 31;
  const int h = lane >> 5;
  const int wrow = wave * 32;
  const size_t pbase = (size_t)b * DIMC * HW + nb0;

  // ---- stage x, shr (transpose-on-load, conflict-free b128 writes) ----
  {
    const int px = lane;
#pragma unroll
    for (int pass = 0; pass < 4; ++pass) {
      const int dblk = pass * 8 + wave;      // 0..31
      const float* xc = x   + pbase + (size_t)(dblk * 8) * HW + px;
      const float* sc = shr + pbase + (size_t)(dblk * 8) * HW + px;
      float vx[8], vs[8];
#pragma unroll
      for (int jj = 0; jj < 8; ++jj) {
        vx[jj] = xc[(size_t)jj * HW];
        vs[jj] = sc[(size_t)jj * HW];
      }
      const int o = dblk * 512 + ((px ^ (dblk & 7)) << 3);
      uint4 wv;
      wv.x = pack2(vx[0], vx[1]); wv.y = pack2(vx[2], vx[3]);
      wv.z = pack2(vx[4], vx[5]); wv.w = pack2(vx[6], vx[7]);
      *(uint4*)&XF[o] = wv;
      uint4 sv;
      sv.x = pack2(vs[0], vs[1]); sv.y = pack2(vs[2], vs[3]);
      sv.z = pack2(vs[4], vs[5]); sv.w = pack2(vs[6], vs[7]);
      *(uint4*)&SF[o] = sv;
    }
  }
  __syncthreads();

  const unsigned short* A1w = A1b + (size_t)(b * 8 + wave) * 8192;
  const unsigned short* A2w = A2b + (size_t)(b * 8 + wave) * 8192;
  const unsigned short* A3w = A3b + (size_t)(b * 8 + wave) * 16384;

  // ---- GEMM2: bb = A2 @ shared  (depth-2 A prefetch) ----
  f32x16 accB0 = (f32x16)0.f, accB1 = (f32x16)0.f;
  {
    bf16x8 ap0 = *(const bf16x8*)(A2w + lane * 8);
    bf16x8 ap1 = *(const bf16x8*)(A2w + 512 + lane * 8);
#pragma unroll
    for (int ks = 0; ks < 16; ++ks) {
      const bf16x8 a = ap0;
      ap0 = ap1;
      if (ks < 14) ap1 = *(const bf16x8*)(A2w + (ks + 2) * 512 + lane * 8);
      const int dblkB = ks * 2 + h;
      const int eb = dblkB * 512 + ((r32 ^ (dblkB & 7)) << 3);
      const bf16x8 b0 = *(const bf16x8*)&SF[eb];
      const bf16x8 b1 = *(const bf16x8*)&SF[eb + 256];
      accB0 = __builtin_amdgcn_mfma_f32_32x32x16_bf16(a, b0, accB0, 0, 0, 0);
      accB1 = __builtin_amdgcn_mfma_f32_32x32x16_bf16(a, b1, accB1, 0, 0, 0);
    }
  }

  // ---- GEMM1: a = A1 @ x  (depth-2 A prefetch) ----
  f32x16 accA0 = (f32x16)0.f, accA1 = (f32x16)0.f;
  {
    bf16x8 ap0 = *(const bf16x8*)(A1w + lane * 8);
    bf16x8 ap1 = *(const bf16x8*)(A1w + 512 + lane * 8);
#pragma unroll
    for (int ks = 0; ks < 16; ++ks) {
      const bf16x8 a = ap0;
      ap0 = ap1;
      if (ks < 14) ap1 = *(const bf16x8*)(A1w + (ks + 2) * 512 + lane * 8);
      const int dblkB = ks * 2 + h;
      const int eb = dblkB * 512 + ((r32 ^ (dblkB & 7)) << 3);
      const bf16x8 b0 = *(const bf16x8*)&XF[eb];
      const bf16x8 b1 = *(const bf16x8*)&XF[eb + 256];
      accA0 = __builtin_amdgcn_mfma_f32_32x32x16_bf16(a, b0, accA0, 0, 0, 0);
      accA1 = __builtin_amdgcn_mfma_f32_32x32x16_bf16(a, b1, accA1, 0, 0, 0);
    }
  }
  __syncthreads();                           // all SF reads done (y overwrites)

  // ---- y = a * silu(bb) -> SF (accA/accB die here) ----
#pragma unroll
  for (int q = 0; q < 4; ++q) {
    const int dblk = wave * 4 + q;
    const int sw = dblk & 7;
    const int base = dblk * 512 + h * 4;
    float y0[4], y1[4];
#pragma unroll
    for (int i = 0; i < 4; ++i) {
      const float bA = accB0[q * 4 + i];
      const float bBv = accB1[q * 4 + i];
      y0[i] = accA0[q * 4 + i] * (bA / (1.f + __expf(-bA)));
      y1[i] = accA1[q * 4 + i] * (bBv / (1.f + __expf(-bBv)));
    }
    uint2 w0; w0.x = pack2(y0[0], y0[1]); w0.y = pack2(y0[2], y0[3]);
    *(uint2*)&SF[base + ((r32 ^ sw) << 3)] = w0;
    uint2 w1; w1.x = pack2(y1[0], y1[1]); w1.y = pack2(y1[2], y1[3]);
    *(uint2*)&SF[base + (((32 + r32) ^ sw) << 3)] = w1;
  }

  // ---- GEMM3 x-half (reads only XF — overlaps other waves' y-writes) ----
  f32x16 accO0 = (f32x16)0.f, accO1 = (f32x16)0.f;
  {
    const unsigned short* A3x = A3w + 16 * 512;
    bf16x8 ap0 = *(const bf16x8*)(A3x + lane * 8);
    bf16x8 ap1 = *(const bf16x8*)(A3x + 512 + lane * 8);
#pragma unroll
    for (int ks = 0; ks < 16; ++ks) {
      const bf16x8 a = ap0;
      ap0 = ap1;
      if (ks < 14) ap1 = *(const bf16x8*)(A3x + (ks + 2) * 512 + lane * 8);
      const int dblkB = ks * 2 + h;
      const int eb = dblkB * 512 + ((r32 ^ (dblkB & 7)) << 3);
      const bf16x8 b0 = *(const bf16x8*)&XF[eb];
      const bf16x8 b1 = *(const bf16x8*)&XF[eb + 256];
      accO0 = __builtin_amdgcn_mfma_f32_32x32x16_bf16(a, b0, accO0, 0, 0, 0);
      accO1 = __builtin_amdgcn_mfma_f32_32x32x16_bf16(a, b1, accO1, 0, 0, 0);
    }
  }
  __syncthreads();                           // Y ready

  // ---- GEMM3 y-half: accO += A3[:, 0:256] @ y  (depth-2 A prefetch) ----
  {
    bf16x8 ap0 = *(const bf16x8*)(A3w + lane * 8);
    bf16x8 ap1 = *(const bf16x8*)(A3w + 512 + lane * 8);
#pragma unroll
    for (int ks = 0; ks < 16; ++ks) {
      const bf16x8 a = ap0;
      ap0 = ap1;
      if (ks < 14) ap1 = *(const bf16x8*)(A3w + (ks + 2) * 512 + lane * 8);
      const int dblkB = ks * 2 + h;
      const int eb = dblkB * 512 + ((r32 ^ (dblkB & 7)) << 3);
      const bf16x8 b0 = *(const bf16x8*)&SF[eb];
      const bf16x8 b1 = *(const bf16x8*)&SF[eb + 256];
      accO0 = __builtin_amdgcn_mfma_f32_32x32x16_bf16(a, b0, accO0, 0, 0, 0);
      accO1 = __builtin_amdgcn_mfma_f32_32x32x16_bf16(a, b1, accO1, 0, 0, 0);
    }
  }

  // ---- store out (fp32): row = wrow + (r&3) + 8*(r>>2) + 4h, col = px ----
  {
    float* ob = out + pbase;
#pragma unroll
    for (int r = 0; r < 16; ++r) {
      const int row = wrow + (r & 3) + 8 * (r >> 2) + 4 * h;
      ob[(size_t)row * HW + r32] = accO0[r];
      ob[(size_t)row * HW + 32 + r32] = accO1[r];
    }
  }
}

// ---------------------------------------------------------------------------
extern "C" void kernel_launch(void* const* d_in, const int* in_sizes, int n_in,
                              void* d_out, int out_size, void* d_ws, size_t ws_size,
                              hipStream_t stream) {
  (void)in_sizes; (void)n_in; (void)out_size; (void)ws_size;
  const float* x   = (const float*)d_in[0];
  const float* shr = (const float*)d_in[1];
  const float* w1  = (const float*)d_in[2];
  const float* b1  = (const float*)d_in[3];
  const float* w2  = (const float*)d_in[4];
  const float* b2  = (const float*)d_in[5];
  const float* gw  = (const float*)d_in[6];
  const float* fgw = (const float*)d_in[7];
  const float* p0  = (const float*)d_in[8];
  const float* p1  = (const float*)d_in[9];
  const float* p2  = (const float*)d_in[10];
  const float* wp  = (const float*)d_in[11];
  float* out = (float*)d_out;

  float* ws    = (float*)d_ws;
  float* xsum  = ws;                         // 2048 f32
  float* hsum  = ws + 2048;                  // 2048 f32
  float* gates = ws + 4096;                  // 32 f32
  float* gsumv = ws + 4128;                  // 8 f32
  int*   sel   = (int*)(ws + 4136);          // 16 ints
  float* q2    = ws + 4152;                  // 131072 f32
  unsigned* A1u = (unsigned*)(ws + 135224);  // 262144 u32 (bf16 pairs)
  unsigned* A2u = A1u + NB * 256 * 128;      // 262144 u32
  unsigned* A3u = A2u + NB * 256 * 128;      // 524288 u32
  float* t1g   = (float*)(A3u + NB * 256 * 256);  // 4096 f32
  float* feg   = t1g + NB * HID;                  // 2048 f32

  k_conv_reduce<<<NB * DIMC, 256, 0, stream>>>(x, xsum, hsum);
  k_gate_t1<<<1024, 256, 0, stream>>>(hsum, w1, b1, t1g);
  k_gate_fe<<<512, 256, 0, stream>>>(t1g, w2, b2, feg);
  k_gate_fin<<<1, 256, 0, stream>>>(xsum, feg, gw, fgw, gates, gsumv, sel);
  k_q2<<<NE * DIMC, 128, 0, stream>>>(wp, p2, q2);
  k_build<<<512, 256, 0, stream>>>(p0, p1, wp, q2, gates, gsumv, sel, A1u, A2u, A3u);
  k_main_mfma<<<2048, 512, 0, stream>>>(x, shr,
      (const unsigned short*)A1u, (const unsigned short*)A2u,
      (const unsigned short*)A3u, out);
}